// Round 15
// baseline (139.556 us; speedup 1.0000x reference)
//
#include <hip/hip_runtime.h>

#define BATCH 64
#define NHEADS 32
#define KVH 8
#define HDIM 128
#define GQA 4          // NHEADS / KVH
#define BLKSZ 16       // paged-cache block size
#define MAXBLK 128     // max blocks per seq
#define MAXLEN 2048
#define SCALE 0.08838834764831845f
#define SCALE_LOG2E 0.12752966f    // SCALE * log2(e): softmax via 2^x, identical ratios

#define CHUNK 64                   // kv positions per partial block (4 cache blocks)
#define NPART (MAXLEN / CHUNK)     // 32
#define GSTRIDE 144                // floats per record: 128 acc + s + pad -> 576B, 64B-aligned
#define SLOT_BYTES 4096u           // KVH*HDIM*4 bytes per slot
#define WS_FLOATS ((size_t)BATCH * NPART * KVH * GQA * GSTRIDE)   // ~38 MB

typedef unsigned int uint;
typedef float f32x4 __attribute__((ext_vector_type(4)));

struct KVBuf { float4 k0, k1, v0, v1; };

// ---- DPP-based 32-lane sum: pure VALU, zero DS-pipe ops --------------------
template<int CTRL>
__device__ __forceinline__ float dppAdd(float x) {
    int y = __builtin_amdgcn_update_dpp(0, __float_as_int(x), CTRL, 0xf, 0xf, false);
    return x + __int_as_float(y);
}

__device__ __forceinline__ float halfSum(float v, bool upper) {
    v = dppAdd<0x111>(v);   // row_shr:1
    v = dppAdd<0x112>(v);   // row_shr:2
    v = dppAdd<0x114>(v);   // row_shr:4
    v = dppAdd<0x118>(v);   // row_shr:8
    v = dppAdd<0x142>(v);   // row_bcast15
    const float lo = __int_as_float(__builtin_amdgcn_readlane(__float_as_int(v), 31));
    const float hi = __int_as_float(__builtin_amdgcn_readlane(__float_as_int(v), 63));
    return upper ? hi : lo;
}

// ---------------- Kernel 1: partial attention over one chunk ----------------
// grid = BATCH*NPART = 2048, block = 256. Half-wave h owns kv-head h; lane i
// owns d=[4i,4i+4). Clean blocks: A/B double-buffered pipeline, now as
// ROLLED loops (round 15): the fully-unrolled 32-pair body was ~45KB of
// straight-line code > 32KB L1I -> continuous I-fetch misses. Rolled form
// is ~5KB: outer (unroll 1) over 4 table blocks, inner (unroll 1) 3-iter
// A/B pipeline + epilogue per 16-slot group.
// Settled lessons: NT loads 4x slower (r9). min-waves=8 halves VGPR, breaks
// reg dbuf (r12). Oversubscription regresses (r13). SW work-queue (r8).
__global__ __launch_bounds__(256, 4) void pa_partial(
    const float* __restrict__ q,
    const float* __restrict__ knew,
    const float* __restrict__ vnew,
    const float* __restrict__ k_cache,
    const float* __restrict__ v_cache,
    const int*   __restrict__ block_tables,
    const int*   __restrict__ context_lens,
    float* __restrict__ ws)
{
    const int bid  = blockIdx.x;
    const int part = bid & (NPART - 1);
    const int b    = bid >> 5;               // NPART = 32

    const int cl = context_lens[b];
    const int n  = cl + 1;
    const int p0 = part * CHUNK;
    if (p0 >= n) return;
    const int pend = min(p0 + CHUNK, n);

    const int tid  = threadIdx.x;
    const int kvh  = tid >> 5;
    const int lane = tid & 31;
    const bool upperHalf = (tid & 32) != 0;
    // head kvh starts at kvh*HDIM floats = kvh*512 bytes; lane owns 16 bytes
    const uint laneByte = ((uint)kvh << 9) + ((uint)lane << 4);

    // Q fragments with SCALE*log2e folded in (softmax computed via 2^x)
    float4 qf[GQA];
    #pragma unroll
    for (int g = 0; g < GQA; ++g) {
        float4 t = *reinterpret_cast<const float4*>(
            &q[(size_t)b * (NHEADS * HDIM) + (size_t)(kvh * GQA + g) * HDIM + lane * 4]);
        t.x *= SCALE_LOG2E; t.y *= SCALE_LOG2E; t.z *= SCALE_LOG2E; t.w *= SCALE_LOG2E;
        qf[g] = t;
    }

    float  s[GQA];
    float4 acc[GQA];
    #pragma unroll
    for (int g = 0; g < GQA; ++g) {
        s[g] = 0.f;
        acc[g] = make_float4(0.f, 0.f, 0.f, 0.f);
    }

    const char* kc8 = reinterpret_cast<const char*>(k_cache);
    const char* vc8 = reinterpret_cast<const char*>(v_cache);

#define CONSUME(P)                                                               \
        {                                                                        \
            float sc0[GQA], sc1[GQA];                                            \
            _Pragma("unroll")                                                    \
            for (int g = 0; g < GQA; ++g) {                                      \
                sc0[g] = buf##P.k0.x * qf[g].x + buf##P.k0.y * qf[g].y           \
                       + buf##P.k0.z * qf[g].z + buf##P.k0.w * qf[g].w;          \
                sc1[g] = buf##P.k1.x * qf[g].x + buf##P.k1.y * qf[g].y           \
                       + buf##P.k1.z * qf[g].z + buf##P.k1.w * qf[g].w;          \
            }                                                                    \
            _Pragma("unroll")                                                    \
            for (int g = 0; g < GQA; ++g) {                                      \
                sc0[g] = halfSum(sc0[g], upperHalf);                             \
                sc1[g] = halfSum(sc1[g], upperHalf);                             \
            }                                                                    \
            _Pragma("unroll")                                                    \
            for (int g = 0; g < GQA; ++g) {                                      \
                const float e0 = __builtin_amdgcn_exp2f(sc0[g]);                 \
                const float e1 = __builtin_amdgcn_exp2f(sc1[g]);                 \
                s[g] += e0 + e1;                                                 \
                acc[g].x += e0 * buf##P.v0.x + e1 * buf##P.v1.x;                 \
                acc[g].y += e0 * buf##P.v0.y + e1 * buf##P.v1.y;                 \
                acc[g].z += e0 * buf##P.v0.z + e1 * buf##P.v1.z;                 \
                acc[g].w += e0 * buf##P.v0.w + e1 * buf##P.v1.w;                 \
            }                                                                    \
        }

    if (p0 + CHUNK <= cl) {
        // ------- clean path: 64 positions = 4 groups of 16 slots, rolled -------
        const int* btp = &block_tables[b * MAXBLK + (p0 >> 4)];
        KVBuf bufA, bufB;

        #pragma unroll 1
        for (int c = 0; c < 4; ++c) {
            const uint base = (uint)btp[c] * (BLKSZ * SLOT_BYTES) + laneByte;
            const char* kb = kc8 + base;
            const char* vb = vc8 + base;

#define ISSUE_AT(P, off)                                                         \
            {                                                                    \
                buf##P.k0 = *reinterpret_cast<const float4*>(kb + (off));        \
                buf##P.k1 = *reinterpret_cast<const float4*>(kb + (off) + 4096); \
                buf##P.v0 = *reinterpret_cast<const float4*>(vb + (off));        \
                buf##P.v1 = *reinterpret_cast<const float4*>(vb + (off) + 4096); \
            }

            // pairs 0..7 of this group; pipeline with 1-pair lead
            ISSUE_AT(A, 0);
            #pragma unroll 1
            for (int j = 0; j < 6; j += 2) {
                ISSUE_AT(B, (j + 1) * 8192);
                CONSUME(A);
                ISSUE_AT(A, (j + 2) * 8192);
                CONSUME(B);
            }
            ISSUE_AT(B, 7 * 8192);
            CONSUME(A);
            CONSUME(B);
#undef ISSUE_AT
        }
    } else {
        // ---------------- dirty path: tail / contains the new token ----------------
        const int* bt = &block_tables[b * MAXBLK];
        const float* knrow = &knew[((size_t)b * KVH + kvh) * HDIM + lane * 4];
        const float* vnrow = &vnew[((size_t)b * KVH + kvh) * HDIM + lane * 4];

        for (int t0 = p0; t0 < pend; t0 += 4) {
            bool valid[4];
            const float* kp[4];
            const float* vp[4];
            #pragma unroll
            for (int j = 0; j < 4; ++j) {
                const int l = t0 + j;                 // uniform across block
                valid[j] = (l < pend);
                if (!valid[j] || l == cl) {
                    kp[j] = knrow; vp[j] = vnrow;
                } else {
                    const int blk = bt[l >> 4];
                    const uint u  = ((uint)blk * BLKSZ + (l & 15)) * SLOT_BYTES + laneByte;
                    kp[j] = reinterpret_cast<const float*>(kc8 + u);
                    vp[j] = reinterpret_cast<const float*>(vc8 + u);
                }
            }

            float4 kf[4], vf[4];
            #pragma unroll
            for (int j = 0; j < 4; ++j) kf[j] = *reinterpret_cast<const float4*>(kp[j]);
            #pragma unroll
            for (int j = 0; j < 4; ++j) vf[j] = *reinterpret_cast<const float4*>(vp[j]);

            float sc[4][GQA];
            #pragma unroll
            for (int j = 0; j < 4; ++j)
                #pragma unroll
                for (int g = 0; g < GQA; ++g)
                    sc[j][g] = kf[j].x * qf[g].x + kf[j].y * qf[g].y
                             + kf[j].z * qf[g].z + kf[j].w * qf[g].w;

            #pragma unroll
            for (int off = 16; off > 0; off >>= 1)
                #pragma unroll
                for (int j = 0; j < 4; ++j)
                    #pragma unroll
                    for (int g = 0; g < GQA; ++g)
                        sc[j][g] += __shfl_xor(sc[j][g], off, 32);

            #pragma unroll
            for (int g = 0; g < GQA; ++g) {
                float p[4];
                #pragma unroll
                for (int j = 0; j < 4; ++j)
                    p[j] = valid[j] ? __builtin_amdgcn_exp2f(sc[j][g]) : 0.f;
                s[g] += (p[0] + p[1]) + (p[2] + p[3]);
                acc[g].x += p[0] * vf[0].x + p[1] * vf[1].x + p[2] * vf[2].x + p[3] * vf[3].x;
                acc[g].y += p[0] * vf[0].y + p[1] * vf[1].y + p[2] * vf[2].y + p[3] * vf[3].y;
                acc[g].z += p[0] * vf[0].z + p[1] * vf[1].z + p[2] * vf[2].z + p[3] * vf[3].z;
                acc[g].w += p[0] * vf[0].w + p[1] * vf[1].w + p[2] * vf[2].w + p[3] * vf[3].w;
            }
        }
    }
#undef CONSUME

    // epilogue: each half-wave owns (kvh, g, d-slice) exclusively -> direct store
    float* rec = ws + ((size_t)(bid * KVH + kvh) * GQA) * GSTRIDE;
    #pragma unroll
    for (int g = 0; g < GQA; ++g)
        *reinterpret_cast<float4*>(rec + (size_t)g * GSTRIDE + lane * 4) = acc[g];
    if (lane == 0) {
        #pragma unroll
        for (int g = 0; g < GQA; ++g) rec[(size_t)g * GSTRIDE + 128] = s[g];
    }
}

// ---------------- Kernel 2: merge partials (plain sums, vectorized) ----------------
// grid = BATCH*KVH (512), block = 128: thread (g = t>>5, lane = t&31) owns
// float4 at dim 4*lane of head-group g. 4-deep unrolled over parts.
__global__ __launch_bounds__(128) void pa_reduce(
    const float* __restrict__ ws,
    const int*   __restrict__ context_lens,
    float* __restrict__ out)
{
    const int bh   = blockIdx.x;
    const int b    = bh >> 3;
    const int kvh  = bh & 7;
    const int t    = threadIdx.x;
    const int g    = t >> 5;
    const int lane = t & 31;

    const int n    = context_lens[b] + 1;
    const int pcnt = (n + CHUNK - 1) / CHUNK;

    const float* base = ws + ((size_t)((b * NPART) * KVH + kvh) * GQA + g) * GSTRIDE;
    const size_t pstride = (size_t)KVH * GQA * GSTRIDE;

    f32x4 O0 = {0,0,0,0}, O1 = {0,0,0,0}, O2 = {0,0,0,0}, O3 = {0,0,0,0};
    float S0 = 0.f, S1 = 0.f, S2 = 0.f, S3 = 0.f;
    int p = 0;
    for (; p + 4 <= pcnt; p += 4) {
        const float* r0 = base + (p + 0) * pstride;
        const float* r1 = base + (p + 1) * pstride;
        const float* r2 = base + (p + 2) * pstride;
        const float* r3 = base + (p + 3) * pstride;
        O0 += *reinterpret_cast<const f32x4*>(r0 + lane * 4);
        O1 += *reinterpret_cast<const f32x4*>(r1 + lane * 4);
        O2 += *reinterpret_cast<const f32x4*>(r2 + lane * 4);
        O3 += *reinterpret_cast<const f32x4*>(r3 + lane * 4);
        S0 += r0[128]; S1 += r1[128]; S2 += r2[128]; S3 += r3[128];
    }
    for (; p < pcnt; ++p) {
        const float* r = base + p * pstride;
        O0 += *reinterpret_cast<const f32x4*>(r + lane * 4);
        S0 += r[128];
    }
    const f32x4 O = (O0 + O1) + (O2 + O3);
    const float S = (S0 + S1) + (S2 + S3);
    const float inv = 1.0f / S;

    float* op = &out[(size_t)b * (NHEADS * HDIM) + (size_t)(kvh * GQA + g) * HDIM + lane * 4];
    *reinterpret_cast<f32x4*>(op) = O * inv;
}

// ---------------- Fallback: single-pass kernel (ws too small) ----------------
__global__ __launch_bounds__(256) void paged_attn_decode(
    const float* __restrict__ q,
    const float* __restrict__ knew,
    const float* __restrict__ vnew,
    const float* __restrict__ k_cache,
    const float* __restrict__ v_cache,
    const int*   __restrict__ block_tables,
    const int*   __restrict__ context_lens,
    float* __restrict__ out)
{
    const int bh   = blockIdx.x;
    const int b    = bh / KVH;
    const int kvh  = bh % KVH;
    const int tid  = threadIdx.x;
    const int hw   = tid >> 5;
    const int lane = tid & 31;

    const int cl = context_lens[b];
    const int n  = cl + 1;

    float4 qf[GQA];
    #pragma unroll
    for (int g = 0; g < GQA; ++g) {
        float4 t = *reinterpret_cast<const float4*>(
            &q[(size_t)b * (NHEADS * HDIM) + (size_t)(kvh * GQA + g) * HDIM + lane * 4]);
        t.x *= SCALE_LOG2E; t.y *= SCALE_LOG2E; t.z *= SCALE_LOG2E; t.w *= SCALE_LOG2E;
        qf[g] = t;
    }

    float  s[GQA];
    float4 acc[GQA];
    #pragma unroll
    for (int g = 0; g < GQA; ++g) { s[g] = 0.f; acc[g] = make_float4(0.f,0.f,0.f,0.f); }

    const int* bt = &block_tables[b * MAXBLK];

    for (int l = hw; l < n; l += 8) {
        const float4* krow;
        const float4* vrow;
        if (l == cl) {
            krow = reinterpret_cast<const float4*>(&knew[(size_t)(b * KVH + kvh) * HDIM]);
            vrow = reinterpret_cast<const float4*>(&vnew[(size_t)(b * KVH + kvh) * HDIM]);
        } else {
            const int    blk = bt[l >> 4];
            const size_t off = (((size_t)blk * BLKSZ + (l & 15)) * KVH + kvh) * HDIM;
            krow = reinterpret_cast<const float4*>(&k_cache[off]);
            vrow = reinterpret_cast<const float4*>(&v_cache[off]);
        }
        const float4 kf = krow[lane];
        const float4 vf = vrow[lane];

        float sc[GQA];
        #pragma unroll
        for (int g = 0; g < GQA; ++g)
            sc[g] = kf.x * qf[g].x + kf.y * qf[g].y + kf.z * qf[g].z + kf.w * qf[g].w;

        #pragma unroll
        for (int off = 16; off > 0; off >>= 1)
            #pragma unroll
            for (int g = 0; g < GQA; ++g)
                sc[g] += __shfl_xor(sc[g], off, 32);

        #pragma unroll
        for (int g = 0; g < GQA; ++g) {
            const float p = __builtin_amdgcn_exp2f(sc[g]);
            s[g] += p;
            acc[g].x += p * vf.x; acc[g].y += p * vf.y;
            acc[g].z += p * vf.z; acc[g].w += p * vf.w;
        }
    }

    __shared__ float lds_s[8][GQA];
    __shared__ float lds_acc[8][GQA][HDIM];

    #pragma unroll
    for (int g = 0; g < GQA; ++g)
        *reinterpret_cast<float4*>(&lds_acc[hw][g][lane * 4]) = acc[g];
    if (lane == 0) {
        #pragma unroll
        for (int g = 0; g < GQA; ++g) lds_s[hw][g] = s[g];
    }
    __syncthreads();

    for (int i = tid; i < GQA * HDIM; i += 256) {
        const int g = i >> 7;
        const int d = i & 127;
        float S = 0.f, O = 0.f;
        #pragma unroll
        for (int h = 0; h < 8; ++h) { S += lds_s[h][g]; O += lds_acc[h][g][d]; }
        out[(size_t)b * (NHEADS * HDIM) + (size_t)(kvh * GQA + g) * HDIM + d] = O / S;
    }
}

extern "C" void kernel_launch(void* const* d_in, const int* in_sizes, int n_in,
                              void* d_out, int out_size, void* d_ws, size_t ws_size,
                              hipStream_t stream) {
    const float* q      = (const float*)d_in[0];
    const float* k      = (const float*)d_in[1];
    const float* v      = (const float*)d_in[2];
    const float* kc     = (const float*)d_in[3];
    const float* vc     = (const float*)d_in[4];
    const int*   bt     = (const int*)d_in[5];
    const int*   clens  = (const int*)d_in[6];
    float*       out    = (float*)d_out;

    if (ws_size >= WS_FLOATS * sizeof(float)) {
        float* ws = (float*)d_ws;
        pa_partial<<<dim3(BATCH * NPART), dim3(256), 0, stream>>>(
            q, k, v, kc, vc, bt, clens, ws);
        pa_reduce<<<dim3(BATCH * KVH), dim3(128), 0, stream>>>(ws, clens, out);
    } else {
        paged_attn_decode<<<dim3(BATCH * KVH), dim3(256), 0, stream>>>(
            q, k, v, kc, vc, bt, clens, out);
    }
}

// Round 16
// 121.012 us; speedup vs baseline: 1.1532x; 1.1532x over previous
//
#include <hip/hip_runtime.h>

#define BATCH 64
#define NHEADS 32
#define KVH 8
#define HDIM 128
#define GQA 4          // NHEADS / KVH
#define BLKSZ 16       // paged-cache block size
#define MAXBLK 128     // max blocks per seq
#define MAXLEN 2048
#define SCALE 0.08838834764831845f

#define CHUNK 64                   // kv positions per partial record (4 cache blocks)
#define MAXITEMS 2048              // worst-case live chunks (all cl = max)
#define GSTRIDE 144                // floats per record: 128 acc + s + pad -> 576B, 64B-aligned
#define SLOT_BYTES 4096u           // KVH*HDIM*4 bytes per slot
#define WS_RECORDS ((size_t)MAXITEMS * KVH * GQA * GSTRIDE)   // floats, ~38 MB
#define WS_FLOATS  (WS_RECORDS + 80)                          // + offs[65] tail

typedef unsigned int uint;
typedef float f32x4 __attribute__((ext_vector_type(4)));

struct KVBuf { float4 k0, k1, v0, v1; };

// ---- DPP-based 32-lane sum: pure VALU, zero DS-pipe ops --------------------
template<int CTRL>
__device__ __forceinline__ float dppAdd(float x) {
    int y = __builtin_amdgcn_update_dpp(0, __float_as_int(x), CTRL, 0xf, 0xf, false);
    return x + __int_as_float(y);
}

__device__ __forceinline__ float halfSum(float v, bool upper) {
    v = dppAdd<0x111>(v);   // row_shr:1
    v = dppAdd<0x112>(v);   // row_shr:2
    v = dppAdd<0x114>(v);   // row_shr:4
    v = dppAdd<0x118>(v);   // row_shr:8
    v = dppAdd<0x142>(v);   // row_bcast15
    const float lo = __int_as_float(__builtin_amdgcn_readlane(__float_as_int(v), 31));
    const float hi = __int_as_float(__builtin_amdgcn_readlane(__float_as_int(v), 63));
    return upper ? hi : lo;
}

// ---------------- Kernel 0: chunk-count prefix scan (1 wave) ----------------
// offs[b] = exclusive prefix of ceil((cl_b+1)/CHUNK); offs[BATCH] = total.
__global__ void pa_scan(const int* __restrict__ context_lens, uint* __restrict__ offs) {
    const int t = threadIdx.x;          // 64 threads = 1 wave
    int cnt = (t < BATCH) ? (context_lens[t] + 1 + CHUNK - 1) / CHUNK : 0;
    #pragma unroll
    for (int o = 1; o < 64; o <<= 1) {
        const int v = __shfl_up(cnt, o, 64);
        if (t >= o) cnt += v;
    }
    offs[t + 1] = (uint)cnt;            // inclusive -> offs[1..64]
    if (t == 0) offs[0] = 0u;
}

// ---------------- Kernel 1: partial attention over one dense chunk ----------------
// grid = MAXITEMS, block = 256. Dense work list: item = bid indexes the
// concatenated live chunks of all sequences (offs from pa_scan) -> every
// block <= total does IDENTICAL 64-position work, densely packed ->
// per-CU load is uniform (the b-major static mapping correlated liveness
// with CU id: CUs owning low `part` got ~8 live chunks, high `part` ~0).
// Half-wave h owns kv-head h; lane i owns d=[4i,4i+4); contiguous 4KB-row
// bursts; fully-unrolled A/B register double-buffer (r11, best known).
// Settled: NT loads 4x slower (r9). min-waves=8 halves VGPR, breaks dbuf
// (r12). CHUNK=32 regresses (r13). Code size neutral (r15).
__global__ __launch_bounds__(256, 4) void pa_partial(
    const float* __restrict__ q,
    const float* __restrict__ knew,
    const float* __restrict__ vnew,
    const float* __restrict__ k_cache,
    const float* __restrict__ v_cache,
    const int*   __restrict__ block_tables,
    const int*   __restrict__ context_lens,
    float* __restrict__ ws,
    const uint*  __restrict__ offs)
{
    const uint item = blockIdx.x;
    if (item >= offs[BATCH]) return;     // beyond live work

    // binary search: b such that offs[b] <= item < offs[b+1]
    int lo = 0, hi = BATCH;
    while (lo + 1 < hi) {
        const int mid = (lo + hi) >> 1;
        if (item >= offs[mid]) lo = mid; else hi = mid;
    }
    const int b    = lo;
    const int part = (int)(item - offs[b]);

    const int cl = context_lens[b];
    const int n  = cl + 1;
    const int p0 = part * CHUNK;
    const int pend = min(p0 + CHUNK, n);

    const int tid  = threadIdx.x;
    const int kvh  = tid >> 5;
    const int lane = tid & 31;
    const bool upperHalf = (tid & 32) != 0;
    // head kvh starts at kvh*HDIM floats = kvh*512 bytes; lane owns 16 bytes
    const uint laneByte = ((uint)kvh << 9) + ((uint)lane << 4);

    // Q fragments with SCALE folded in
    float4 qf[GQA];
    #pragma unroll
    for (int g = 0; g < GQA; ++g) {
        float4 t = *reinterpret_cast<const float4*>(
            &q[(size_t)b * (NHEADS * HDIM) + (size_t)(kvh * GQA + g) * HDIM + lane * 4]);
        t.x *= SCALE; t.y *= SCALE; t.z *= SCALE; t.w *= SCALE;
        qf[g] = t;
    }

    float  s[GQA];
    float4 acc[GQA];
    #pragma unroll
    for (int g = 0; g < GQA; ++g) {
        s[g] = 0.f;
        acc[g] = make_float4(0.f, 0.f, 0.f, 0.f);
    }

    const char* kc8 = reinterpret_cast<const char*>(k_cache);
    const char* vc8 = reinterpret_cast<const char*>(v_cache);

    if (p0 + CHUNK <= cl) {
        // ---------------- clean path: 64 positions, no masking ----------------
        int blkv[4];
        #pragma unroll
        for (int c = 0; c < 4; ++c)
            blkv[c] = block_tables[b * MAXBLK + (p0 >> 4) + c];

        KVBuf bufA, bufB;

#define ISSUE(P, i)                                                              \
        {                                                                        \
            const uint u0 = ((uint)blkv[(2*(i)) >> 4] * BLKSZ + ((2*(i)) & 15)) * SLOT_BYTES + laneByte; \
            const uint u1 = ((uint)blkv[(2*(i)+1) >> 4] * BLKSZ + ((2*(i)+1) & 15)) * SLOT_BYTES + laneByte; \
            buf##P.k0 = *reinterpret_cast<const float4*>(kc8 + u0);              \
            buf##P.k1 = *reinterpret_cast<const float4*>(kc8 + u1);              \
            buf##P.v0 = *reinterpret_cast<const float4*>(vc8 + u0);              \
            buf##P.v1 = *reinterpret_cast<const float4*>(vc8 + u1);              \
        }

#define CONSUME(P)                                                               \
        {                                                                        \
            float sc0[GQA], sc1[GQA];                                            \
            _Pragma("unroll")                                                    \
            for (int g = 0; g < GQA; ++g) {                                      \
                sc0[g] = buf##P.k0.x * qf[g].x + buf##P.k0.y * qf[g].y           \
                       + buf##P.k0.z * qf[g].z + buf##P.k0.w * qf[g].w;          \
                sc1[g] = buf##P.k1.x * qf[g].x + buf##P.k1.y * qf[g].y           \
                       + buf##P.k1.z * qf[g].z + buf##P.k1.w * qf[g].w;          \
            }                                                                    \
            _Pragma("unroll")                                                    \
            for (int g = 0; g < GQA; ++g) {                                      \
                sc0[g] = halfSum(sc0[g], upperHalf);                             \
                sc1[g] = halfSum(sc1[g], upperHalf);                             \
            }                                                                    \
            _Pragma("unroll")                                                    \
            for (int g = 0; g < GQA; ++g) {                                      \
                const float e0 = __expf(sc0[g]);                                 \
                const float e1 = __expf(sc1[g]);                                 \
                s[g] += e0 + e1;                                                 \
                acc[g].x += e0 * buf##P.v0.x + e1 * buf##P.v1.x;                 \
                acc[g].y += e0 * buf##P.v0.y + e1 * buf##P.v1.y;                 \
                acc[g].z += e0 * buf##P.v0.z + e1 * buf##P.v1.z;                 \
                acc[g].w += e0 * buf##P.v0.w + e1 * buf##P.v1.w;                 \
            }                                                                    \
        }

        ISSUE(A, 0);
        #pragma unroll
        for (int i = 0; i < 31; ++i) {
            if (i & 1) { ISSUE(A, i + 1); CONSUME(B); }
            else       { ISSUE(B, i + 1); CONSUME(A); }
        }
        CONSUME(B);   // pair 31 was issued into B at i=30
#undef ISSUE
#undef CONSUME
    } else {
        // ---------------- dirty path: last chunk (contains the new token) ----------------
        const int* bt = &block_tables[b * MAXBLK];
        const float* knrow = &knew[((size_t)b * KVH + kvh) * HDIM + lane * 4];
        const float* vnrow = &vnew[((size_t)b * KVH + kvh) * HDIM + lane * 4];

        for (int t0 = p0; t0 < pend; t0 += 4) {
            bool valid[4];
            const float* kp[4];
            const float* vp[4];
            #pragma unroll
            for (int j = 0; j < 4; ++j) {
                const int l = t0 + j;                 // uniform across block
                valid[j] = (l < pend);
                if (!valid[j] || l == cl) {
                    kp[j] = knrow; vp[j] = vnrow;
                } else {
                    const int blk = bt[l >> 4];
                    const uint u  = ((uint)blk * BLKSZ + (l & 15)) * SLOT_BYTES + laneByte;
                    kp[j] = reinterpret_cast<const float*>(kc8 + u);
                    vp[j] = reinterpret_cast<const float*>(vc8 + u);
                }
            }

            float4 kf[4], vf[4];
            #pragma unroll
            for (int j = 0; j < 4; ++j) kf[j] = *reinterpret_cast<const float4*>(kp[j]);
            #pragma unroll
            for (int j = 0; j < 4; ++j) vf[j] = *reinterpret_cast<const float4*>(vp[j]);

            float sc[4][GQA];
            #pragma unroll
            for (int j = 0; j < 4; ++j)
                #pragma unroll
                for (int g = 0; g < GQA; ++g)
                    sc[j][g] = kf[j].x * qf[g].x + kf[j].y * qf[g].y
                             + kf[j].z * qf[g].z + kf[j].w * qf[g].w;

            #pragma unroll
            for (int off = 16; off > 0; off >>= 1)
                #pragma unroll
                for (int j = 0; j < 4; ++j)
                    #pragma unroll
                    for (int g = 0; g < GQA; ++g)
                        sc[j][g] += __shfl_xor(sc[j][g], off, 32);

            #pragma unroll
            for (int g = 0; g < GQA; ++g) {
                float p[4];
                #pragma unroll
                for (int j = 0; j < 4; ++j)
                    p[j] = valid[j] ? __expf(sc[j][g]) : 0.f;
                s[g] += (p[0] + p[1]) + (p[2] + p[3]);
                acc[g].x += p[0] * vf[0].x + p[1] * vf[1].x + p[2] * vf[2].x + p[3] * vf[3].x;
                acc[g].y += p[0] * vf[0].y + p[1] * vf[1].y + p[2] * vf[2].y + p[3] * vf[3].y;
                acc[g].z += p[0] * vf[0].z + p[1] * vf[1].z + p[2] * vf[2].z + p[3] * vf[3].z;
                acc[g].w += p[0] * vf[0].w + p[1] * vf[1].w + p[2] * vf[2].w + p[3] * vf[3].w;
            }
        }
    }

    // epilogue: record indexed by dense item id
    float* rec = ws + ((size_t)(item * KVH + kvh) * GQA) * GSTRIDE;
    #pragma unroll
    for (int g = 0; g < GQA; ++g)
        *reinterpret_cast<float4*>(rec + (size_t)g * GSTRIDE + lane * 4) = acc[g];
    if (lane == 0) {
        #pragma unroll
        for (int g = 0; g < GQA; ++g) rec[(size_t)g * GSTRIDE + 128] = s[g];
    }
}

// ---------------- Kernel 2: merge partials (plain sums, vectorized) ----------------
// grid = BATCH*KVH (512), block = 128. Records of seq b are CONSECUTIVE
// [offs[b], offs[b+1]) -> better locality than the sparse layout.
__global__ __launch_bounds__(128) void pa_reduce(
    const float* __restrict__ ws,
    const uint*  __restrict__ offs,
    float* __restrict__ out)
{
    const int bh   = blockIdx.x;
    const int b    = bh >> 3;
    const int kvh  = bh & 7;
    const int t    = threadIdx.x;
    const int g    = t >> 5;
    const int lane = t & 31;

    const uint i0   = offs[b];
    const int  pcnt = (int)(offs[b + 1] - i0);

    const float* base = ws + ((size_t)(i0 * KVH + kvh) * GQA + g) * GSTRIDE;
    const size_t pstride = (size_t)KVH * GQA * GSTRIDE;

    f32x4 O0 = {0,0,0,0}, O1 = {0,0,0,0}, O2 = {0,0,0,0}, O3 = {0,0,0,0};
    float S0 = 0.f, S1 = 0.f, S2 = 0.f, S3 = 0.f;
    int p = 0;
    for (; p + 4 <= pcnt; p += 4) {
        const float* r0 = base + (p + 0) * pstride;
        const float* r1 = base + (p + 1) * pstride;
        const float* r2 = base + (p + 2) * pstride;
        const float* r3 = base + (p + 3) * pstride;
        O0 += *reinterpret_cast<const f32x4*>(r0 + lane * 4);
        O1 += *reinterpret_cast<const f32x4*>(r1 + lane * 4);
        O2 += *reinterpret_cast<const f32x4*>(r2 + lane * 4);
        O3 += *reinterpret_cast<const f32x4*>(r3 + lane * 4);
        S0 += r0[128]; S1 += r1[128]; S2 += r2[128]; S3 += r3[128];
    }
    for (; p < pcnt; ++p) {
        const float* r = base + p * pstride;
        O0 += *reinterpret_cast<const f32x4*>(r + lane * 4);
        S0 += r[128];
    }
    const f32x4 O = (O0 + O1) + (O2 + O3);
    const float S = (S0 + S1) + (S2 + S3);
    const float inv = 1.0f / S;

    float* op = &out[(size_t)b * (NHEADS * HDIM) + (size_t)(kvh * GQA + g) * HDIM + lane * 4];
    *reinterpret_cast<f32x4*>(op) = O * inv;
}

// ---------------- Fallback: single-pass kernel (ws too small) ----------------
__global__ __launch_bounds__(256) void paged_attn_decode(
    const float* __restrict__ q,
    const float* __restrict__ knew,
    const float* __restrict__ vnew,
    const float* __restrict__ k_cache,
    const float* __restrict__ v_cache,
    const int*   __restrict__ block_tables,
    const int*   __restrict__ context_lens,
    float* __restrict__ out)
{
    const int bh   = blockIdx.x;
    const int b    = bh / KVH;
    const int kvh  = bh % KVH;
    const int tid  = threadIdx.x;
    const int hw   = tid >> 5;
    const int lane = tid & 31;

    const int cl = context_lens[b];
    const int n  = cl + 1;

    float4 qf[GQA];
    #pragma unroll
    for (int g = 0; g < GQA; ++g) {
        float4 t = *reinterpret_cast<const float4*>(
            &q[(size_t)b * (NHEADS * HDIM) + (size_t)(kvh * GQA + g) * HDIM + lane * 4]);
        t.x *= SCALE; t.y *= SCALE; t.z *= SCALE; t.w *= SCALE;
        qf[g] = t;
    }

    float  s[GQA];
    float4 acc[GQA];
    #pragma unroll
    for (int g = 0; g < GQA; ++g) { s[g] = 0.f; acc[g] = make_float4(0.f,0.f,0.f,0.f); }

    const int* bt = &block_tables[b * MAXBLK];

    for (int l = hw; l < n; l += 8) {
        const float4* krow;
        const float4* vrow;
        if (l == cl) {
            krow = reinterpret_cast<const float4*>(&knew[(size_t)(b * KVH + kvh) * HDIM]);
            vrow = reinterpret_cast<const float4*>(&vnew[(size_t)(b * KVH + kvh) * HDIM]);
        } else {
            const int    blk = bt[l >> 4];
            const size_t off = (((size_t)blk * BLKSZ + (l & 15)) * KVH + kvh) * HDIM;
            krow = reinterpret_cast<const float4*>(&k_cache[off]);
            vrow = reinterpret_cast<const float4*>(&v_cache[off]);
        }
        const float4 kf = krow[lane];
        const float4 vf = vrow[lane];

        float sc[GQA];
        #pragma unroll
        for (int g = 0; g < GQA; ++g)
            sc[g] = kf.x * qf[g].x + kf.y * qf[g].y + kf.z * qf[g].z + kf.w * qf[g].w;

        #pragma unroll
        for (int off = 16; off > 0; off >>= 1)
            #pragma unroll
            for (int g = 0; g < GQA; ++g)
                sc[g] += __shfl_xor(sc[g], off, 32);

        #pragma unroll
        for (int g = 0; g < GQA; ++g) {
            const float p = __expf(sc[g]);
            s[g] += p;
            acc[g].x += p * vf.x; acc[g].y += p * vf.y;
            acc[g].z += p * vf.z; acc[g].w += p * vf.w;
        }
    }

    __shared__ float lds_s[8][GQA];
    __shared__ float lds_acc[8][GQA][HDIM];

    #pragma unroll
    for (int g = 0; g < GQA; ++g)
        *reinterpret_cast<float4*>(&lds_acc[hw][g][lane * 4]) = acc[g];
    if (lane == 0) {
        #pragma unroll
        for (int g = 0; g < GQA; ++g) lds_s[hw][g] = s[g];
    }
    __syncthreads();

    for (int i = tid; i < GQA * HDIM; i += 256) {
        const int g = i >> 7;
        const int d = i & 127;
        float S = 0.f, O = 0.f;
        #pragma unroll
        for (int h = 0; h < 8; ++h) { S += lds_s[h][g]; O += lds_acc[h][g][d]; }
        out[(size_t)b * (NHEADS * HDIM) + (size_t)(kvh * GQA + g) * HDIM + d] = O / S;
    }
}

extern "C" void kernel_launch(void* const* d_in, const int* in_sizes, int n_in,
                              void* d_out, int out_size, void* d_ws, size_t ws_size,
                              hipStream_t stream) {
    const float* q      = (const float*)d_in[0];
    const float* k      = (const float*)d_in[1];
    const float* v      = (const float*)d_in[2];
    const float* kc     = (const float*)d_in[3];
    const float* vc     = (const float*)d_in[4];
    const int*   bt     = (const int*)d_in[5];
    const int*   clens  = (const int*)d_in[6];
    float*       out    = (float*)d_out;

    if (ws_size >= WS_FLOATS * sizeof(float)) {
        float* ws   = (float*)d_ws;
        uint*  offs = (uint*)(ws + WS_RECORDS);
        pa_scan<<<dim3(1), dim3(64), 0, stream>>>(clens, offs);
        pa_partial<<<dim3(MAXITEMS), dim3(256), 0, stream>>>(
            q, k, v, kc, vc, bt, clens, ws, offs);
        pa_reduce<<<dim3(BATCH * KVH), dim3(128), 0, stream>>>(ws, offs, out);
    } else {
        paged_attn_decode<<<dim3(BATCH * KVH), dim3(256), 0, stream>>>(
            q, k, v, kc, vc, bt, clens, out);
    }
}

// Round 17
// 117.615 us; speedup vs baseline: 1.1866x; 1.0289x over previous
//
#include <hip/hip_runtime.h>
#include <hip/hip_fp16.h>

#define BATCH 64
#define NHEADS 32
#define KVH 8
#define HDIM 128
#define GQA 4          // NHEADS / KVH
#define BLKSZ 16       // paged-cache block size
#define MAXBLK 128     // max blocks per seq
#define MAXLEN 2048
#define SCALE 0.08838834764831845f

#define CHUNK 64                   // kv positions per partial record (4 cache blocks)
#define MAXITEMS 2048              // worst-case live chunks
#define REC_BYTES 320u             // 128 fp16 acc (256B) + f32 S + pad -> 64B-aligned
#define SLOT_BYTES 4096u           // KVH*HDIM*4 bytes per slot
#define WS_REC_FLOATS ((size_t)MAXITEMS * KVH * GQA * (REC_BYTES / 4))  // ~21 MB
#define WS_FLOATS (WS_REC_FLOATS + 80)                                   // + offs[65]

typedef unsigned int uint;
typedef float f32x4 __attribute__((ext_vector_type(4)));

struct KVBuf { float4 k0, k1, v0, v1; };

// ---- DPP-based 32-lane sum: pure VALU, zero DS-pipe ops --------------------
template<int CTRL>
__device__ __forceinline__ float dppAdd(float x) {
    int y = __builtin_amdgcn_update_dpp(0, __float_as_int(x), CTRL, 0xf, 0xf, false);
    return x + __int_as_float(y);
}

__device__ __forceinline__ float halfSum(float v, bool upper) {
    v = dppAdd<0x111>(v);   // row_shr:1
    v = dppAdd<0x112>(v);   // row_shr:2
    v = dppAdd<0x114>(v);   // row_shr:4
    v = dppAdd<0x118>(v);   // row_shr:8
    v = dppAdd<0x142>(v);   // row_bcast15
    const float lo = __int_as_float(__builtin_amdgcn_readlane(__float_as_int(v), 31));
    const float hi = __int_as_float(__builtin_amdgcn_readlane(__float_as_int(v), 63));
    return upper ? hi : lo;
}

// ---------------- Kernel 0: chunk-count prefix scan (1 wave) ----------------
__global__ void pa_scan(const int* __restrict__ context_lens, uint* __restrict__ offs) {
    const int t = threadIdx.x;          // 64 threads = 1 wave
    int cnt = (t < BATCH) ? (context_lens[t] + 1 + CHUNK - 1) / CHUNK : 0;
    #pragma unroll
    for (int o = 1; o < 64; o <<= 1) {
        const int v = __shfl_up(cnt, o, 64);
        if (t >= o) cnt += v;
    }
    offs[t + 1] = (uint)cnt;            // inclusive -> offs[1..64]
    if (t == 0) offs[0] = 0u;
}

// ---------------- Kernel 1: partial attention over one dense chunk ----------------
// grid = MAXITEMS, block = 256. Dense work list (r16, +11%): item = bid
// indexes concatenated live chunks -> uniform per-CU load. Half-wave h owns
// kv-head h; lane i owns d=[4i,4i+4); contiguous 4KB-row bursts; unrolled
// A/B register double-buffer (r11). Records stored fp16 (r17): halves ws
// round-trip traffic; error contribution ~4e-5 << 3e-2 threshold.
// Settled: NT loads 4x slower (r9). min-waves=8 halves VGPR, breaks dbuf
// (r12). CHUNK=32 regresses (r13). Code size neutral (r15).
__global__ __launch_bounds__(256, 4) void pa_partial(
    const float* __restrict__ q,
    const float* __restrict__ knew,
    const float* __restrict__ vnew,
    const float* __restrict__ k_cache,
    const float* __restrict__ v_cache,
    const int*   __restrict__ block_tables,
    const int*   __restrict__ context_lens,
    float* __restrict__ ws,
    const uint*  __restrict__ offs)
{
    const uint item = blockIdx.x;
    if (item >= offs[BATCH]) return;     // beyond live work

    // binary search: b such that offs[b] <= item < offs[b+1]
    int lo = 0, hi = BATCH;
    while (lo + 1 < hi) {
        const int mid = (lo + hi) >> 1;
        if (item >= offs[mid]) lo = mid; else hi = mid;
    }
    const int b    = lo;
    const int part = (int)(item - offs[b]);

    const int cl = context_lens[b];
    const int n  = cl + 1;
    const int p0 = part * CHUNK;
    const int pend = min(p0 + CHUNK, n);

    const int tid  = threadIdx.x;
    const int kvh  = tid >> 5;
    const int lane = tid & 31;
    const bool upperHalf = (tid & 32) != 0;
    // head kvh starts at kvh*HDIM floats = kvh*512 bytes; lane owns 16 bytes
    const uint laneByte = ((uint)kvh << 9) + ((uint)lane << 4);

    // Q fragments with SCALE folded in
    float4 qf[GQA];
    #pragma unroll
    for (int g = 0; g < GQA; ++g) {
        float4 t = *reinterpret_cast<const float4*>(
            &q[(size_t)b * (NHEADS * HDIM) + (size_t)(kvh * GQA + g) * HDIM + lane * 4]);
        t.x *= SCALE; t.y *= SCALE; t.z *= SCALE; t.w *= SCALE;
        qf[g] = t;
    }

    float  s[GQA];
    float4 acc[GQA];
    #pragma unroll
    for (int g = 0; g < GQA; ++g) {
        s[g] = 0.f;
        acc[g] = make_float4(0.f, 0.f, 0.f, 0.f);
    }

    const char* kc8 = reinterpret_cast<const char*>(k_cache);
    const char* vc8 = reinterpret_cast<const char*>(v_cache);

    if (p0 + CHUNK <= cl) {
        // ---------------- clean path: 64 positions, no masking ----------------
        int blkv[4];
        #pragma unroll
        for (int c = 0; c < 4; ++c)
            blkv[c] = block_tables[b * MAXBLK + (p0 >> 4) + c];

        KVBuf bufA, bufB;

#define ISSUE(P, i)                                                              \
        {                                                                        \
            const uint u0 = ((uint)blkv[(2*(i)) >> 4] * BLKSZ + ((2*(i)) & 15)) * SLOT_BYTES + laneByte; \
            const uint u1 = ((uint)blkv[(2*(i)+1) >> 4] * BLKSZ + ((2*(i)+1) & 15)) * SLOT_BYTES + laneByte; \
            buf##P.k0 = *reinterpret_cast<const float4*>(kc8 + u0);              \
            buf##P.k1 = *reinterpret_cast<const float4*>(kc8 + u1);              \
            buf##P.v0 = *reinterpret_cast<const float4*>(vc8 + u0);              \
            buf##P.v1 = *reinterpret_cast<const float4*>(vc8 + u1);              \
        }

#define CONSUME(P)                                                               \
        {                                                                        \
            float sc0[GQA], sc1[GQA];                                            \
            _Pragma("unroll")                                                    \
            for (int g = 0; g < GQA; ++g) {                                      \
                sc0[g] = buf##P.k0.x * qf[g].x + buf##P.k0.y * qf[g].y           \
                       + buf##P.k0.z * qf[g].z + buf##P.k0.w * qf[g].w;          \
                sc1[g] = buf##P.k1.x * qf[g].x + buf##P.k1.y * qf[g].y           \
                       + buf##P.k1.z * qf[g].z + buf##P.k1.w * qf[g].w;          \
            }                                                                    \
            _Pragma("unroll")                                                    \
            for (int g = 0; g < GQA; ++g) {                                      \
                sc0[g] = halfSum(sc0[g], upperHalf);                             \
                sc1[g] = halfSum(sc1[g], upperHalf);                             \
            }                                                                    \
            _Pragma("unroll")                                                    \
            for (int g = 0; g < GQA; ++g) {                                      \
                const float e0 = __expf(sc0[g]);                                 \
                const float e1 = __expf(sc1[g]);                                 \
                s[g] += e0 + e1;                                                 \
                acc[g].x += e0 * buf##P.v0.x + e1 * buf##P.v1.x;                 \
                acc[g].y += e0 * buf##P.v0.y + e1 * buf##P.v1.y;                 \
                acc[g].z += e0 * buf##P.v0.z + e1 * buf##P.v1.z;                 \
                acc[g].w += e0 * buf##P.v0.w + e1 * buf##P.v1.w;                 \
            }                                                                    \
        }

        ISSUE(A, 0);
        #pragma unroll
        for (int i = 0; i < 31; ++i) {
            if (i & 1) { ISSUE(A, i + 1); CONSUME(B); }
            else       { ISSUE(B, i + 1); CONSUME(A); }
        }
        CONSUME(B);   // pair 31 was issued into B at i=30
#undef ISSUE
#undef CONSUME
    } else {
        // ---------------- dirty path: last chunk (contains the new token) ----------------
        const int* bt = &block_tables[b * MAXBLK];
        const float* knrow = &knew[((size_t)b * KVH + kvh) * HDIM + lane * 4];
        const float* vnrow = &vnew[((size_t)b * KVH + kvh) * HDIM + lane * 4];

        for (int t0 = p0; t0 < pend; t0 += 4) {
            bool valid[4];
            const float* kp[4];
            const float* vp[4];
            #pragma unroll
            for (int j = 0; j < 4; ++j) {
                const int l = t0 + j;                 // uniform across block
                valid[j] = (l < pend);
                if (!valid[j] || l == cl) {
                    kp[j] = knrow; vp[j] = vnrow;
                } else {
                    const int blk = bt[l >> 4];
                    const uint u  = ((uint)blk * BLKSZ + (l & 15)) * SLOT_BYTES + laneByte;
                    kp[j] = reinterpret_cast<const float*>(kc8 + u);
                    vp[j] = reinterpret_cast<const float*>(vc8 + u);
                }
            }

            float4 kf[4], vf[4];
            #pragma unroll
            for (int j = 0; j < 4; ++j) kf[j] = *reinterpret_cast<const float4*>(kp[j]);
            #pragma unroll
            for (int j = 0; j < 4; ++j) vf[j] = *reinterpret_cast<const float4*>(vp[j]);

            float sc[4][GQA];
            #pragma unroll
            for (int j = 0; j < 4; ++j)
                #pragma unroll
                for (int g = 0; g < GQA; ++g)
                    sc[j][g] = kf[j].x * qf[g].x + kf[j].y * qf[g].y
                             + kf[j].z * qf[g].z + kf[j].w * qf[g].w;

            #pragma unroll
            for (int off = 16; off > 0; off >>= 1)
                #pragma unroll
                for (int j = 0; j < 4; ++j)
                    #pragma unroll
                    for (int g = 0; g < GQA; ++g)
                        sc[j][g] += __shfl_xor(sc[j][g], off, 32);

            #pragma unroll
            for (int g = 0; g < GQA; ++g) {
                float p[4];
                #pragma unroll
                for (int j = 0; j < 4; ++j)
                    p[j] = valid[j] ? __expf(sc[j][g]) : 0.f;
                s[g] += (p[0] + p[1]) + (p[2] + p[3]);
                acc[g].x += p[0] * vf[0].x + p[1] * vf[1].x + p[2] * vf[2].x + p[3] * vf[3].x;
                acc[g].y += p[0] * vf[0].y + p[1] * vf[1].y + p[2] * vf[2].y + p[3] * vf[3].y;
                acc[g].z += p[0] * vf[0].z + p[1] * vf[1].z + p[2] * vf[2].z + p[3] * vf[3].z;
                acc[g].w += p[0] * vf[0].w + p[1] * vf[1].w + p[2] * vf[2].w + p[3] * vf[3].w;
            }
        }
    }

    // epilogue: fp16 record indexed by dense item id; lane owns 8B at lane*8
    char* rec = reinterpret_cast<char*>(ws)
              + (size_t)(item * KVH + kvh) * GQA * REC_BYTES;
    #pragma unroll
    for (int g = 0; g < GQA; ++g) {
        __half2 h01 = __floats2half2_rn(acc[g].x, acc[g].y);
        __half2 h23 = __floats2half2_rn(acc[g].z, acc[g].w);
        uint2 pk;
        pk.x = *reinterpret_cast<uint*>(&h01);
        pk.y = *reinterpret_cast<uint*>(&h23);
        *reinterpret_cast<uint2*>(rec + (size_t)g * REC_BYTES + lane * 8) = pk;
    }
    if (lane == 0) {
        #pragma unroll
        for (int g = 0; g < GQA; ++g)
            *reinterpret_cast<float*>(rec + (size_t)g * REC_BYTES + 256) = s[g];
    }
}

// ---------------- Kernel 2: merge partials (fp16 records, plain sums) ----------------
// grid = BATCH*KVH (512), block = 128: thread (g = t>>5, lane = t&31) owns
// dims [4*lane, 4*lane+4). Records of seq b are consecutive [offs[b], offs[b+1]).
__global__ __launch_bounds__(128) void pa_reduce(
    const float* __restrict__ ws,
    const uint*  __restrict__ offs,
    float* __restrict__ out)
{
    const int bh   = blockIdx.x;
    const int b    = bh >> 3;
    const int kvh  = bh & 7;
    const int t    = threadIdx.x;
    const int g    = t >> 5;
    const int lane = t & 31;

    const uint i0   = offs[b];
    const int  pcnt = (int)(offs[b + 1] - i0);

    const char* base = reinterpret_cast<const char*>(ws)
                     + ((size_t)(i0 * KVH + kvh) * GQA + g) * REC_BYTES;
    const size_t pstride = (size_t)KVH * GQA * REC_BYTES;

    f32x4 O0 = {0,0,0,0}, O1 = {0,0,0,0}, O2 = {0,0,0,0}, O3 = {0,0,0,0};
    float S0 = 0.f, S1 = 0.f, S2 = 0.f, S3 = 0.f;

#define ACCREC(Ov, Sv, rp)                                                       \
    {                                                                            \
        const uint2 pk = *reinterpret_cast<const uint2*>((rp) + lane * 8);       \
        const float2 f01 = __half22float2(*reinterpret_cast<const __half2*>(&pk.x)); \
        const float2 f23 = __half22float2(*reinterpret_cast<const __half2*>(&pk.y)); \
        Ov.x += f01.x; Ov.y += f01.y; Ov.z += f23.x; Ov.w += f23.y;              \
        Sv += *reinterpret_cast<const float*>((rp) + 256);                       \
    }

    int p = 0;
    for (; p + 4 <= pcnt; p += 4) {
        const char* r0 = base + (size_t)(p + 0) * pstride;
        const char* r1 = base + (size_t)(p + 1) * pstride;
        const char* r2 = base + (size_t)(p + 2) * pstride;
        const char* r3 = base + (size_t)(p + 3) * pstride;
        ACCREC(O0, S0, r0);
        ACCREC(O1, S1, r1);
        ACCREC(O2, S2, r2);
        ACCREC(O3, S3, r3);
    }
    for (; p < pcnt; ++p) {
        const char* r = base + (size_t)p * pstride;
        ACCREC(O0, S0, r);
    }
#undef ACCREC

    const f32x4 O = (O0 + O1) + (O2 + O3);
    const float S = (S0 + S1) + (S2 + S3);
    const float inv = 1.0f / S;

    float* op = &out[(size_t)b * (NHEADS * HDIM) + (size_t)(kvh * GQA + g) * HDIM + lane * 4];
    *reinterpret_cast<f32x4*>(op) = O * inv;
}

// ---------------- Fallback: single-pass kernel (ws too small) ----------------
__global__ __launch_bounds__(256) void paged_attn_decode(
    const float* __restrict__ q,
    const float* __restrict__ knew,
    const float* __restrict__ vnew,
    const float* __restrict__ k_cache,
    const float* __restrict__ v_cache,
    const int*   __restrict__ block_tables,
    const int*   __restrict__ context_lens,
    float* __restrict__ out)
{
    const int bh   = blockIdx.x;
    const int b    = bh / KVH;
    const int kvh  = bh % KVH;
    const int tid  = threadIdx.x;
    const int hw   = tid >> 5;
    const int lane = tid & 31;

    const int cl = context_lens[b];
    const int n  = cl + 1;

    float4 qf[GQA];
    #pragma unroll
    for (int g = 0; g < GQA; ++g) {
        float4 t = *reinterpret_cast<const float4*>(
            &q[(size_t)b * (NHEADS * HDIM) + (size_t)(kvh * GQA + g) * HDIM + lane * 4]);
        t.x *= SCALE; t.y *= SCALE; t.z *= SCALE; t.w *= SCALE;
        qf[g] = t;
    }

    float  s[GQA];
    float4 acc[GQA];
    #pragma unroll
    for (int g = 0; g < GQA; ++g) { s[g] = 0.f; acc[g] = make_float4(0.f,0.f,0.f,0.f); }

    const int* bt = &block_tables[b * MAXBLK];

    for (int l = hw; l < n; l += 8) {
        const float4* krow;
        const float4* vrow;
        if (l == cl) {
            krow = reinterpret_cast<const float4*>(&knew[(size_t)(b * KVH + kvh) * HDIM]);
            vrow = reinterpret_cast<const float4*>(&vnew[(size_t)(b * KVH + kvh) * HDIM]);
        } else {
            const int    blk = bt[l >> 4];
            const size_t off = (((size_t)blk * BLKSZ + (l & 15)) * KVH + kvh) * HDIM;
            krow = reinterpret_cast<const float4*>(&k_cache[off]);
            vrow = reinterpret_cast<const float4*>(&v_cache[off]);
        }
        const float4 kf = krow[lane];
        const float4 vf = vrow[lane];

        float sc[GQA];
        #pragma unroll
        for (int g = 0; g < GQA; ++g)
            sc[g] = kf.x * qf[g].x + kf.y * qf[g].y + kf.z * qf[g].z + kf.w * qf[g].w;

        #pragma unroll
        for (int off = 16; off > 0; off >>= 1)
            #pragma unroll
            for (int g = 0; g < GQA; ++g)
                sc[g] += __shfl_xor(sc[g], off, 32);

        #pragma unroll
        for (int g = 0; g < GQA; ++g) {
            const float p = __expf(sc[g]);
            s[g] += p;
            acc[g].x += p * vf.x; acc[g].y += p * vf.y;
            acc[g].z += p * vf.z; acc[g].w += p * vf.w;
        }
    }

    __shared__ float lds_s[8][GQA];
    __shared__ float lds_acc[8][GQA][HDIM];

    #pragma unroll
    for (int g = 0; g < GQA; ++g)
        *reinterpret_cast<float4*>(&lds_acc[hw][g][lane * 4]) = acc[g];
    if (lane == 0) {
        #pragma unroll
        for (int g = 0; g < GQA; ++g) lds_s[hw][g] = s[g];
    }
    __syncthreads();

    for (int i = tid; i < GQA * HDIM; i += 256) {
        const int g = i >> 7;
        const int d = i & 127;
        float S = 0.f, O = 0.f;
        #pragma unroll
        for (int h = 0; h < 8; ++h) { S += lds_s[h][g]; O += lds_acc[h][g][d]; }
        out[(size_t)b * (NHEADS * HDIM) + (size_t)(kvh * GQA + g) * HDIM + d] = O / S;
    }
}

extern "C" void kernel_launch(void* const* d_in, const int* in_sizes, int n_in,
                              void* d_out, int out_size, void* d_ws, size_t ws_size,
                              hipStream_t stream) {
    const float* q      = (const float*)d_in[0];
    const float* k      = (const float*)d_in[1];
    const float* v      = (const float*)d_in[2];
    const float* kc     = (const float*)d_in[3];
    const float* vc     = (const float*)d_in[4];
    const int*   bt     = (const int*)d_in[5];
    const int*   clens  = (const int*)d_in[6];
    float*       out    = (float*)d_out;

    if (ws_size >= WS_FLOATS * sizeof(float)) {
        float* ws   = (float*)d_ws;
        uint*  offs = (uint*)(ws + WS_REC_FLOATS);
        pa_scan<<<dim3(1), dim3(64), 0, stream>>>(clens, offs);
        pa_partial<<<dim3(MAXITEMS), dim3(256), 0, stream>>>(
            q, k, v, kc, vc, bt, clens, ws, offs);
        pa_reduce<<<dim3(BATCH * KVH), dim3(128), 0, stream>>>(ws, offs, out);
    } else {
        paged_attn_decode<<<dim3(BATCH * KVH), dim3(256), 0, stream>>>(
            q, k, v, kc, vc, bt, clens, out);
    }
}